// Round 9
// baseline (197.058 us; speedup 1.0000x reference)
//
#include <hip/hip_runtime.h>
#include <math.h>
#include <stdint.h>

#define B_ 16
#define D_ 1024
#define T_ 4096
#define CS_ 1024
#define CD_ 8

// ---------- numpy-mimicking fp32 helpers ----------
__device__ __forceinline__ float f_tree8(const float r[8]) {
  return __fadd_rn(
      __fadd_rn(__fadd_rn(r[0], r[1]), __fadd_rn(r[2], r[3])),
      __fadd_rn(__fadd_rn(r[4], r[5]), __fadd_rn(r[6], r[7])));
}
__device__ __forceinline__ float f_sumsq8(const float x[8]) {
  float s[8];
#pragma unroll
  for (int k = 0; k < 8; ++k) s[k] = __fmul_rn(x[k], x[k]);
  return f_tree8(s);
}

// ---------- setup: normalize W_in, W_out, codebook; pack tables ----------
// ws layout:
//   WTd  : double[1024][8]   (W_in^T, fp32-rounded widened to f64)  @ 0      (65536 B)
//   cb16 : float [1024][16]  ({cbn[8], scb, pad})                   @ 65536  (65536 B)
//   wo16 : float [1024][16]  ({woutn[8], b_out, pad})               @ 131072 (65536 B)
//   lossp: float [512]                                              @ 196608 (2048 B)
__global__ __launch_bounds__(1024) void vq_setup(
    const float* __restrict__ cb, const float* __restrict__ g_in,
    const float* __restrict__ v_in, const float* __restrict__ g_out,
    const float* __restrict__ v_out, const float* __restrict__ b_out,
    double* __restrict__ WTd, float* __restrict__ cb16,
    float* __restrict__ wo16) {
  __shared__ float sv[8 * 1024];
  __shared__ float leafs[64];
  __shared__ float den[8];
  const int tid = threadIdx.x;

  for (int i = tid; i < 8 * 1024; i += 1024) sv[i] = v_in[i];
  __syncthreads();

  // numpy pairwise_sum(1024): 8 leaf blocks of 128 (8-accumulator pattern),
  // combined with the same binary tree as tree8.
  if (tid < 64) {
    const int c = tid >> 3, l = tid & 7;
    const float* a = sv + c * 1024 + l * 128;
    float r[8];
#pragma unroll
    for (int k = 0; k < 8; ++k) r[k] = __fmul_rn(a[k], a[k]);
    for (int i = 8; i < 128; i += 8) {
#pragma unroll
      for (int k = 0; k < 8; ++k)
        r[k] = __fadd_rn(r[k], __fmul_rn(a[i + k], a[i + k]));
    }
    leafs[c * 8 + l] = f_tree8(r);
  }
  __syncthreads();
  if (tid < 8) {
    const float* L = leafs + tid * 8;
    float lr[8];
#pragma unroll
    for (int k = 0; k < 8; ++k) lr[k] = L[k];
    const float s = f_tree8(lr);
    den[tid] = fmaxf(__fsqrt_rn(s), 1e-12f);
  }
  __syncthreads();

  if (tid < 1024) {
#pragma unroll
    for (int c = 0; c < 8; ++c) {
      const float w = __fdiv_rn(__fmul_rn(g_in[c], sv[c * 1024 + tid]), den[c]);
      WTd[tid * 8 + c] = (double)w;
    }
    {
      const float* cr = cb + tid * 8;
      float q[8];
#pragma unroll
      for (int c = 0; c < 8; ++c) q[c] = cr[c];
      const float nn = f_sumsq8(q);
      const float dd = fmaxf(__fsqrt_rn(nn), 1e-12f);
      float qn[8];
#pragma unroll
      for (int c = 0; c < 8; ++c) {
        qn[c] = __fdiv_rn(q[c], dd);
        cb16[tid * 16 + c] = qn[c];
      }
      cb16[tid * 16 + 8] = f_sumsq8(qn);
#pragma unroll
      for (int c = 9; c < 16; ++c) cb16[tid * 16 + c] = 0.f;
    }
    {
      const float* vr = v_out + tid * 8;
      float w[8];
#pragma unroll
      for (int c = 0; c < 8; ++c) w[c] = vr[c];
      const float n2 = f_sumsq8(w);
      const float d2 = fmaxf(__fsqrt_rn(n2), 1e-12f);
      const float go = g_out[tid];
#pragma unroll
      for (int c = 0; c < 8; ++c)
        wo16[tid * 16 + c] = __fdiv_rn(__fmul_rn(go, w[c]), d2);
      wo16[tid * 16 + 8] = b_out[tid];
#pragma unroll
      for (int c = 9; c < 16; ++c) wo16[tid * 16 + c] = 0.f;
    }
  }
}

// ---------- K1: z_e + argmin + loss (no out-projection) ----------
// Grid: 512 blocks x 1024 threads (16 waves). Block owns 128 consecutive t
// of one b; each LANE owns 2 consecutive t (float2 z loads). Wave q covers
// the same 128 t but d/code SLICE [q*64, (q+1)*64). R7-proven phase 1
// (8-deep prefetch, NO sched_barrier fences -> no spills), R8-style wave-0
// combine (cheap LDS) WITHOUT fences. Writes only idx + loss partials.
__global__ __launch_bounds__(1024, 8) void vq_ze(
    const float* __restrict__ z, const float* __restrict__ cbraw,
    const float* __restrict__ b_in, const double* __restrict__ WTd,
    const float* __restrict__ cb16, float* __restrict__ oidx,
    float* __restrict__ lossp) {
  __shared__ double accb[8704];  // 68 KB: partials 64K + tot 4K (disjoint)
  const int tid = threadIdx.x;
  const int q0 = __builtin_amdgcn_readfirstlane(tid >> 6);  // wave 0..15
  const int tl = tid & 63;
  const int blk = blockIdx.x;  // 512 = 16 b * 32 tiles
  const int b = blk >> 5;
  const int tile = blk & 31;
  const int t0 = tile * 128 + tl * 2;  // this lane's t-pair

  // ---- phase 1: partial z_e in f64 over this wave's 64-d slice ----
  const float2* zp2 =
      (const float2*)(z + ((size_t)b * D_ + (size_t)q0 * 64) * T_ + t0);
  const double* wd = WTd + (size_t)q0 * 512;  // uniform -> s_load

  double acc0[8], acc1[8];
#pragma unroll
  for (int c = 0; c < 8; ++c) { acc0[c] = 0.0; acc1[c] = 0.0; }

  float2 zA[8], zB[8];
#pragma unroll
  for (int u = 0; u < 8; ++u) zA[u] = zp2[(size_t)u * (T_ / 2)];

#pragma unroll
  for (int dc = 0; dc < 64; dc += 16) {
    // prefetch group B (d = dc+8 .. dc+15)
#pragma unroll
    for (int u = 0; u < 8; ++u)
      zB[u] = zp2[(size_t)(dc + 8 + u) * (T_ / 2)];
    // compute group A
#pragma unroll
    for (int u = 0; u < 8; ++u) {
      const double* w = wd + (size_t)(dc + u) * 8;
      const double zx = (double)zA[u].x, zy = (double)zA[u].y;
#pragma unroll
      for (int c = 0; c < 8; ++c) {
        acc0[c] = fma(zx, w[c], acc0[c]);
        acc1[c] = fma(zy, w[c], acc1[c]);
      }
    }
    // prefetch group A for next chunk
    if (dc + 16 < 64) {
#pragma unroll
      for (int u = 0; u < 8; ++u)
        zA[u] = zp2[(size_t)(dc + 16 + u) * (T_ / 2)];
    }
    // compute group B
#pragma unroll
    for (int u = 0; u < 8; ++u) {
      const double* w = wd + (size_t)(dc + 8 + u) * 8;
      const double zx = (double)zB[u].x, zy = (double)zB[u].y;
#pragma unroll
      for (int c = 0; c < 8; ++c) {
        acc0[c] = fma(zx, w[c], acc0[c]);
        acc1[c] = fma(zy, w[c], acc1[c]);
      }
    }
  }

  // ---- 16-slice f64 combine: wave 0 reduces (ascending slice order,
  //      bit-identical to R7), result broadcast via disjoint LDS ----
  double2* accb2 = (double2*)accb;       // partials: [0, 4096) double2
  double2* totb = accb2 + 4096;          // tot: [4096, 4352) double2
  double tot0[8], tot1[8];
#pragma unroll
  for (int half = 0; half < 2; ++half) {
    const int c0 = half * 4;
#pragma unroll
    for (int c = 0; c < 4; ++c) {
      double2 v; v.x = acc0[c0 + c]; v.y = acc1[c0 + c];
      accb2[c * 1024 + tid] = v;
    }
    __syncthreads();
    if (tid < 64) {
#pragma unroll
      for (int c = 0; c < 4; ++c) {
        const double2* row = accb2 + c * 1024 + tl;
        double2 s = row[0];
#pragma unroll
        for (int qq = 1; qq < 16; ++qq) {
          const double2 v = row[qq * 64];
          s.x = s.x + v.x;  // ascending slice order
          s.y = s.y + v.y;
        }
        totb[c * 64 + tl] = s;
      }
    }
    __syncthreads();
#pragma unroll
    for (int c = 0; c < 4; ++c) {
      const double2 s = totb[c * 64 + tl];
      tot0[c0 + c] = s.x; tot1[c0 + c] = s.y;
    }
  }

  // materialize fp32 z_e (+ b_in), normalize (numpy-mimicked), per t
  float e0[8], e1[8], en0[8], en1[8];
#pragma unroll
  for (int c = 0; c < 8; ++c) {
    e0[c] = __fadd_rn((float)tot0[c], b_in[c]);
    e1[c] = __fadd_rn((float)tot1[c], b_in[c]);
  }
  const float n20 = f_sumsq8(e0), n21 = f_sumsq8(e1);
  const float dn0 = fmaxf(__fsqrt_rn(n20), 1e-12f);
  const float dn1 = fmaxf(__fsqrt_rn(n21), 1e-12f);
#pragma unroll
  for (int c = 0; c < 8; ++c) {
    en0[c] = __fdiv_rn(e0[c], dn0);
    en1[c] = __fdiv_rn(e1[c], dn1);
  }
  const float s_enc0 = f_sumsq8(en0), s_enc1 = f_sumsq8(en1);

  // ---- phase 2: nearest code over this wave's 64-code slice ----
  const int j0 = q0 * 64;
  float best0 = INFINITY, best1 = INFINITY;
  int bj0 = j0, bj1 = j0;
  {
    const float* cbq = cb16 + (size_t)j0 * 16;  // uniform -> s_load
#pragma unroll 4
    for (int jj = 0; jj < 64; ++jj) {
      const float* row = cbq + jj * 16;
      const float4 lo = *(const float4*)(row);
      const float4 hi = *(const float4*)(row + 4);
      const float sc = row[8];
      float d0 = 0.f, d1 = 0.f;
      d0 = fmaf(en0[0], lo.x, d0); d1 = fmaf(en1[0], lo.x, d1);
      d0 = fmaf(en0[1], lo.y, d0); d1 = fmaf(en1[1], lo.y, d1);
      d0 = fmaf(en0[2], lo.z, d0); d1 = fmaf(en1[2], lo.z, d1);
      d0 = fmaf(en0[3], lo.w, d0); d1 = fmaf(en1[3], lo.w, d1);
      d0 = fmaf(en0[4], hi.x, d0); d1 = fmaf(en1[4], hi.x, d1);
      d0 = fmaf(en0[5], hi.y, d0); d1 = fmaf(en1[5], hi.y, d1);
      d0 = fmaf(en0[6], hi.z, d0); d1 = fmaf(en1[6], hi.z, d1);
      d0 = fmaf(en0[7], hi.w, d0); d1 = fmaf(en1[7], hi.w, d1);
      const float dist0 =
          __fadd_rn(__fsub_rn(s_enc0, __fmul_rn(2.0f, d0)), sc);
      const float dist1 =
          __fadd_rn(__fsub_rn(s_enc1, __fmul_rn(2.0f, d1)), sc);
      if (dist0 < best0) { best0 = dist0; bj0 = j0 + jj; }
      if (dist1 < best1) { best1 = dist1; bj1 = j0 + jj; }
    }
  }

  // ---- candidate combine: all waves deposit, wave 0 scans (ascending qq,
  //      strict <) and is the only consumer (idx write + loss) ----
  float* distf0 = (float*)accb;                  // 1024 f32
  int* candj0 = (int*)((char*)accb + 4096);      // 1024 i32
  float* distf1 = (float*)((char*)accb + 8192);  // 1024 f32
  int* candj1 = (int*)((char*)accb + 12288);     // 1024 i32
  distf0[tid] = best0; candj0[tid] = bj0;
  distf1[tid] = best1; candj1[tid] = bj1;
  __syncthreads();

  if (tid < 64) {
    float bd0 = distf0[tl], bd1 = distf1[tl];
    int bi0 = candj0[tl], bi1 = candj1[tl];
#pragma unroll
    for (int qq = 1; qq < 16; ++qq) {
      float dd = distf0[qq * 64 + tl];
      int jj = candj0[qq * 64 + tl];
      if (dd < bd0) { bd0 = dd; bi0 = jj; }  // strict <: low slice wins
      dd = distf1[qq * 64 + tl];
      jj = candj1[qq * 64 + tl];
      if (dd < bd1) { bd1 = dd; bi1 = jj; }
    }
    float2 iv; iv.x = (float)bi0; iv.y = (float)bi1;
    *(float2*)(oidx + (size_t)b * T_ + t0) = iv;

    // raw codebook rows (divergent 32B gathers) + loss partial
    float cq0[8], cq1[8];
    const float* cp0 = cbraw + (size_t)bi0 * 8;
    const float* cp1 = cbraw + (size_t)bi1 * 8;
#pragma unroll
    for (int c = 0; c < 8; ++c) { cq0[c] = cp0[c]; cq1[c] = cp1[c]; }
    float lsum = 0.f;
#pragma unroll
    for (int c = 0; c < 8; ++c) {
      const float df0 = __fsub_rn(e0[c], cq0[c]);
      lsum = fmaf(df0, df0, lsum);
    }
#pragma unroll
    for (int c = 0; c < 8; ++c) {
      const float df1 = __fsub_rn(e1[c], cq1[c]);
      lsum = fmaf(df1, df1, lsum);
    }
#pragma unroll
    for (int off = 32; off > 0; off >>= 1)
      lsum += __shfl_down(lsum, off, 64);
    if (tl == 0) lossp[blk] = lsum;
  }
}

// ---------- K2: back-projection, pure write-streamer ----------
// Grid: 1024 blocks x 256 threads = 16 b x 4 tq (1024-t tiles) x 16 dq
// (64-d tiles). Each thread owns 4 consecutive t and 64 d: gathers its 4
// raw codebook rows once (L2-hot 32 KB table), reads W_out rows via
// uniform s_load, writes float4 (16 B/lane = 1 KB/wave stores).
__global__ __launch_bounds__(256) void vq_out(
    const float* __restrict__ cbraw, const float* __restrict__ wo16,
    const float* __restrict__ oidx, float* __restrict__ out) {
  const int tid = threadIdx.x;
  const int blk = blockIdx.x;  // b*64 + tq*16 + dq
  const int b = blk >> 6;
  const int tq = (blk >> 4) & 3;
  const int dq = blk & 15;
  const int t0 = tq * 1024 + tid * 4;
  const int d0 = dq * 64;

  const float4 iv = *(const float4*)(oidx + (size_t)b * T_ + t0);
  const int i0 = (int)iv.x, i1 = (int)iv.y, i2 = (int)iv.z, i3 = (int)iv.w;

  float cq0[8], cq1[8], cq2[8], cq3[8];
  {
    const float* p0 = cbraw + (size_t)i0 * 8;
    const float* p1 = cbraw + (size_t)i1 * 8;
    const float* p2 = cbraw + (size_t)i2 * 8;
    const float* p3 = cbraw + (size_t)i3 * 8;
#pragma unroll
    for (int c = 0; c < 8; ++c) {
      cq0[c] = p0[c]; cq1[c] = p1[c]; cq2[c] = p2[c]; cq3[c] = p3[c];
    }
  }

  const float* woq = wo16 + (size_t)d0 * 16;  // uniform -> s_load
  float* op = out + ((size_t)b * D_ + d0) * T_ + t0;
#pragma unroll 4
  for (int d = 0; d < 64; ++d) {
    const float* row = woq + d * 16;
    const float4 lo = *(const float4*)(row);
    const float4 hi = *(const float4*)(row + 4);
    const float bo = row[8];
    float o0 = 0.f, o1 = 0.f, o2 = 0.f, o3 = 0.f;
    o0 = fmaf(cq0[0], lo.x, o0); o1 = fmaf(cq1[0], lo.x, o1);
    o2 = fmaf(cq2[0], lo.x, o2); o3 = fmaf(cq3[0], lo.x, o3);
    o0 = fmaf(cq0[1], lo.y, o0); o1 = fmaf(cq1[1], lo.y, o1);
    o2 = fmaf(cq2[1], lo.y, o2); o3 = fmaf(cq3[1], lo.y, o3);
    o0 = fmaf(cq0[2], lo.z, o0); o1 = fmaf(cq1[2], lo.z, o1);
    o2 = fmaf(cq2[2], lo.z, o2); o3 = fmaf(cq3[2], lo.z, o3);
    o0 = fmaf(cq0[3], lo.w, o0); o1 = fmaf(cq1[3], lo.w, o1);
    o2 = fmaf(cq2[3], lo.w, o2); o3 = fmaf(cq3[3], lo.w, o3);
    o0 = fmaf(cq0[4], hi.x, o0); o1 = fmaf(cq1[4], hi.x, o1);
    o2 = fmaf(cq2[4], hi.x, o2); o3 = fmaf(cq3[4], hi.x, o3);
    o0 = fmaf(cq0[5], hi.y, o0); o1 = fmaf(cq1[5], hi.y, o1);
    o2 = fmaf(cq2[5], hi.y, o2); o3 = fmaf(cq3[5], hi.y, o3);
    o0 = fmaf(cq0[6], hi.z, o0); o1 = fmaf(cq1[6], hi.z, o1);
    o2 = fmaf(cq2[6], hi.z, o2); o3 = fmaf(cq3[6], hi.z, o3);
    o0 = fmaf(cq0[7], hi.w, o0); o1 = fmaf(cq1[7], hi.w, o1);
    o2 = fmaf(cq2[7], hi.w, o2); o3 = fmaf(cq3[7], hi.w, o3);
    float4 ov;
    ov.x = __fadd_rn(o0, bo); ov.y = __fadd_rn(o1, bo);
    ov.z = __fadd_rn(o2, bo); ov.w = __fadd_rn(o3, bo);
    *(float4*)(op + (size_t)d * T_) = ov;
  }
}

// ---------- finalize loss ----------
__global__ __launch_bounds__(64) void vq_fin(const float* __restrict__ lossp,
                                             float* __restrict__ oloss) {
  const int tid = threadIdx.x;
  if (tid < B_) {
    float s = 0.f;
    for (int i = 0; i < 32; ++i) s += lossp[tid * 32 + i];
    oloss[tid] = s * (1.25f / 32768.0f);
  }
}

extern "C" void kernel_launch(void* const* d_in, const int* in_sizes, int n_in,
                              void* d_out, int out_size, void* d_ws,
                              size_t ws_size, hipStream_t stream) {
  (void)in_sizes; (void)n_in; (void)out_size; (void)ws_size;
  const float* z = (const float*)d_in[0];
  const float* cb = (const float*)d_in[1];
  const float* g_in = (const float*)d_in[2];
  const float* v_in = (const float*)d_in[3];
  const float* b_in = (const float*)d_in[4];
  const float* g_out = (const float*)d_in[5];
  const float* v_out = (const float*)d_in[6];
  const float* b_out = (const float*)d_in[7];
  float* out = (float*)d_out;

  char* ws = (char*)d_ws;
  double* WTd = (double*)ws;              // 65536 B
  float* cb16 = (float*)(ws + 65536);     // 65536 B
  float* wo16 = (float*)(ws + 131072);    // 65536 B
  float* lossp = (float*)(ws + 196608);   // 2048 B

  float* oidx = out + (size_t)B_ * D_ * T_;
  float* oloss = oidx + (size_t)B_ * T_;

  vq_setup<<<1, 1024, 0, stream>>>(cb, g_in, v_in, g_out, v_out, b_out, WTd,
                                   cb16, wo16);
  vq_ze<<<512, 1024, 0, stream>>>(z, cb, b_in, WTd, cb16, oidx, lossp);
  vq_out<<<1024, 256, 0, stream>>>(cb, wo16, oidx, out);
  vq_fin<<<1, 64, 0, stream>>>(lossp, oloss);
}

// Round 10
// 148.429 us; speedup vs baseline: 1.3276x; 1.3276x over previous
//
#include <hip/hip_runtime.h>
#include <math.h>
#include <stdint.h>

#define B_ 16
#define D_ 1024
#define T_ 4096
#define CS_ 1024
#define CD_ 8

// ---------- numpy-mimicking fp32 helpers ----------
__device__ __forceinline__ float f_tree8(const float r[8]) {
  return __fadd_rn(
      __fadd_rn(__fadd_rn(r[0], r[1]), __fadd_rn(r[2], r[3])),
      __fadd_rn(__fadd_rn(r[4], r[5]), __fadd_rn(r[6], r[7])));
}
__device__ __forceinline__ float f_sumsq8(const float x[8]) {
  float s[8];
#pragma unroll
  for (int k = 0; k < 8; ++k) s[k] = __fmul_rn(x[k], x[k]);
  return f_tree8(s);
}

// ---------- setup: normalize W_in, W_out, codebook; pack tables ----------
// ws layout:
//   WTd  : double[1024][8]   (W_in^T, fp32-rounded widened to f64)  @ 0      (65536 B)
//   cb16 : float [1024][16]  ({cbn[8], scb, pad})                   @ 65536  (65536 B)
//   wo16 : float [1024][16]  ({woutn[8], b_out, pad})               @ 131072 (65536 B)
//   lossp: float [512]                                              @ 196608 (2048 B)
__global__ __launch_bounds__(1024) void vq_setup(
    const float* __restrict__ cb, const float* __restrict__ g_in,
    const float* __restrict__ v_in, const float* __restrict__ g_out,
    const float* __restrict__ v_out, const float* __restrict__ b_out,
    double* __restrict__ WTd, float* __restrict__ cb16,
    float* __restrict__ wo16) {
  __shared__ float sv[8 * 1024];
  __shared__ float leafs[64];
  __shared__ float den[8];
  const int tid = threadIdx.x;

  for (int i = tid; i < 8 * 1024; i += 1024) sv[i] = v_in[i];
  __syncthreads();

  // numpy pairwise_sum(1024): 8 leaf blocks of 128 (8-accumulator pattern),
  // combined with the same binary tree as tree8.
  if (tid < 64) {
    const int c = tid >> 3, l = tid & 7;
    const float* a = sv + c * 1024 + l * 128;
    float r[8];
#pragma unroll
    for (int k = 0; k < 8; ++k) r[k] = __fmul_rn(a[k], a[k]);
    for (int i = 8; i < 128; i += 8) {
#pragma unroll
      for (int k = 0; k < 8; ++k)
        r[k] = __fadd_rn(r[k], __fmul_rn(a[i + k], a[i + k]));
    }
    leafs[c * 8 + l] = f_tree8(r);
  }
  __syncthreads();
  if (tid < 8) {
    const float* L = leafs + tid * 8;
    float lr[8];
#pragma unroll
    for (int k = 0; k < 8; ++k) lr[k] = L[k];
    const float s = f_tree8(lr);
    den[tid] = fmaxf(__fsqrt_rn(s), 1e-12f);
  }
  __syncthreads();

  if (tid < 1024) {
#pragma unroll
    for (int c = 0; c < 8; ++c) {
      const float w = __fdiv_rn(__fmul_rn(g_in[c], sv[c * 1024 + tid]), den[c]);
      WTd[tid * 8 + c] = (double)w;
    }
    {
      const float* cr = cb + tid * 8;
      float q[8];
#pragma unroll
      for (int c = 0; c < 8; ++c) q[c] = cr[c];
      const float nn = f_sumsq8(q);
      const float dd = fmaxf(__fsqrt_rn(nn), 1e-12f);
      float qn[8];
#pragma unroll
      for (int c = 0; c < 8; ++c) {
        qn[c] = __fdiv_rn(q[c], dd);
        cb16[tid * 16 + c] = qn[c];
      }
      cb16[tid * 16 + 8] = f_sumsq8(qn);
#pragma unroll
      for (int c = 9; c < 16; ++c) cb16[tid * 16 + c] = 0.f;
    }
    {
      const float* vr = v_out + tid * 8;
      float w[8];
#pragma unroll
      for (int c = 0; c < 8; ++c) w[c] = vr[c];
      const float n2 = f_sumsq8(w);
      const float d2 = fmaxf(__fsqrt_rn(n2), 1e-12f);
      const float go = g_out[tid];
#pragma unroll
      for (int c = 0; c < 8; ++c)
        wo16[tid * 16 + c] = __fdiv_rn(__fmul_rn(go, w[c]), d2);
      wo16[tid * 16 + 8] = b_out[tid];
#pragma unroll
      for (int c = 9; c < 16; ++c) wo16[tid * 16 + c] = 0.f;
    }
  }
}

// ---------- main kernel (fused; R7 structure + wave-0 combine) ----------
// Grid: 512 blocks x 1024 threads (16 waves). Block owns 128 consecutive t
// of one b; each LANE owns 2 consecutive t (float2 z loads / out stores).
// Wave q covers the same 128 t but d/code SLICE [q*64, (q+1)*64).
// R10 = R7 (8-deep prefetch, NO fences) + wave-0-only f64 combine and
// candidate scan with LDS broadcast (R8's good idea minus its spill-causing
// fences). Fused P3 keeps cross-block fetch/write pipe overlap (R9's split
// serialized the phases globally and regressed).
__global__ __launch_bounds__(1024, 8) void vq_main(
    const float* __restrict__ z, const float* __restrict__ cbraw,
    const float* __restrict__ b_in, const double* __restrict__ WTd,
    const float* __restrict__ cb16, const float* __restrict__ wo16,
    float* __restrict__ out, float* __restrict__ oidx,
    float* __restrict__ lossp) {
  __shared__ double accb[8704];  // 68 KB: partials 64K + tot/ibuf 4K
  const int tid = threadIdx.x;
  const int q0 = __builtin_amdgcn_readfirstlane(tid >> 6);  // wave 0..15
  const int tl = tid & 63;
  const int blk = blockIdx.x;  // 512 = 16 b * 32 tiles
  const int b = blk >> 5;
  const int tile = blk & 31;
  const int t0 = tile * 128 + tl * 2;  // this lane's t-pair

  // ---- phase 1: partial z_e in f64 over this wave's 64-d slice ----
  const float2* zp2 =
      (const float2*)(z + ((size_t)b * D_ + (size_t)q0 * 64) * T_ + t0);
  const double* wd = WTd + (size_t)q0 * 512;  // uniform -> s_load

  double acc0[8], acc1[8];
#pragma unroll
  for (int c = 0; c < 8; ++c) { acc0[c] = 0.0; acc1[c] = 0.0; }

  float2 zA[8], zB[8];
#pragma unroll
  for (int u = 0; u < 8; ++u) zA[u] = zp2[(size_t)u * (T_ / 2)];

#pragma unroll
  for (int dc = 0; dc < 64; dc += 16) {
    // prefetch group B (d = dc+8 .. dc+15)
#pragma unroll
    for (int u = 0; u < 8; ++u)
      zB[u] = zp2[(size_t)(dc + 8 + u) * (T_ / 2)];
    // compute group A
#pragma unroll
    for (int u = 0; u < 8; ++u) {
      const double* w = wd + (size_t)(dc + u) * 8;
      const double zx = (double)zA[u].x, zy = (double)zA[u].y;
#pragma unroll
      for (int c = 0; c < 8; ++c) {
        acc0[c] = fma(zx, w[c], acc0[c]);
        acc1[c] = fma(zy, w[c], acc1[c]);
      }
    }
    // prefetch group A for next chunk
    if (dc + 16 < 64) {
#pragma unroll
      for (int u = 0; u < 8; ++u)
        zA[u] = zp2[(size_t)(dc + 16 + u) * (T_ / 2)];
    }
    // compute group B
#pragma unroll
    for (int u = 0; u < 8; ++u) {
      const double* w = wd + (size_t)(dc + 8 + u) * 8;
      const double zx = (double)zB[u].x, zy = (double)zB[u].y;
#pragma unroll
      for (int c = 0; c < 8; ++c) {
        acc0[c] = fma(zx, w[c], acc0[c]);
        acc1[c] = fma(zy, w[c], acc1[c]);
      }
    }
  }

  // ---- 16-slice f64 combine: wave 0 reduces (ascending slice order,
  //      bit-identical to R7), result broadcast via disjoint LDS ----
  double2* accb2 = (double2*)accb;       // partials: [0, 4096) double2
  double2* totb = accb2 + 4096;          // tot: [4096, 4352) double2
  double tot0[8], tot1[8];
#pragma unroll
  for (int half = 0; half < 2; ++half) {
    const int c0 = half * 4;
#pragma unroll
    for (int c = 0; c < 4; ++c) {
      double2 v; v.x = acc0[c0 + c]; v.y = acc1[c0 + c];
      accb2[c * 1024 + tid] = v;
    }
    __syncthreads();
    if (tid < 64) {
#pragma unroll
      for (int c = 0; c < 4; ++c) {
        const double2* row = accb2 + c * 1024 + tl;
        double2 s = row[0];
#pragma unroll
        for (int qq = 1; qq < 16; ++qq) {
          const double2 v = row[qq * 64];
          s.x = s.x + v.x;  // ascending slice order
          s.y = s.y + v.y;
        }
        totb[c * 64 + tl] = s;
      }
    }
    __syncthreads();
#pragma unroll
    for (int c = 0; c < 4; ++c) {
      const double2 s = totb[c * 64 + tl];
      tot0[c0 + c] = s.x; tot1[c0 + c] = s.y;
    }
  }

  // materialize fp32 z_e (+ b_in), normalize (numpy-mimicked), per t
  float e0[8], e1[8], en0[8], en1[8];
#pragma unroll
  for (int c = 0; c < 8; ++c) {
    e0[c] = __fadd_rn((float)tot0[c], b_in[c]);
    e1[c] = __fadd_rn((float)tot1[c], b_in[c]);
  }
  const float n20 = f_sumsq8(e0), n21 = f_sumsq8(e1);
  const float dn0 = fmaxf(__fsqrt_rn(n20), 1e-12f);
  const float dn1 = fmaxf(__fsqrt_rn(n21), 1e-12f);
#pragma unroll
  for (int c = 0; c < 8; ++c) {
    en0[c] = __fdiv_rn(e0[c], dn0);
    en1[c] = __fdiv_rn(e1[c], dn1);
  }
  const float s_enc0 = f_sumsq8(en0), s_enc1 = f_sumsq8(en1);

  // ---- phase 2: nearest code over this wave's 64-code slice ----
  const int j0 = q0 * 64;
  float best0 = INFINITY, best1 = INFINITY;
  int bj0 = j0, bj1 = j0;
  {
    const float* cbq = cb16 + (size_t)j0 * 16;  // uniform -> s_load
#pragma unroll 4
    for (int jj = 0; jj < 64; ++jj) {
      const float* row = cbq + jj * 16;
      const float4 lo = *(const float4*)(row);
      const float4 hi = *(const float4*)(row + 4);
      const float sc = row[8];
      float d0 = 0.f, d1 = 0.f;
      d0 = fmaf(en0[0], lo.x, d0); d1 = fmaf(en1[0], lo.x, d1);
      d0 = fmaf(en0[1], lo.y, d0); d1 = fmaf(en1[1], lo.y, d1);
      d0 = fmaf(en0[2], lo.z, d0); d1 = fmaf(en1[2], lo.z, d1);
      d0 = fmaf(en0[3], lo.w, d0); d1 = fmaf(en1[3], lo.w, d1);
      d0 = fmaf(en0[4], hi.x, d0); d1 = fmaf(en1[4], hi.x, d1);
      d0 = fmaf(en0[5], hi.y, d0); d1 = fmaf(en1[5], hi.y, d1);
      d0 = fmaf(en0[6], hi.z, d0); d1 = fmaf(en1[6], hi.z, d1);
      d0 = fmaf(en0[7], hi.w, d0); d1 = fmaf(en1[7], hi.w, d1);
      const float dist0 =
          __fadd_rn(__fsub_rn(s_enc0, __fmul_rn(2.0f, d0)), sc);
      const float dist1 =
          __fadd_rn(__fsub_rn(s_enc1, __fmul_rn(2.0f, d1)), sc);
      if (dist0 < best0) { best0 = dist0; bj0 = j0 + jj; }
      if (dist1 < best1) { best1 = dist1; bj1 = j0 + jj; }
    }
  }

  // ---- candidate combine: wave 0 scans (ascending qq, strict <), writes
  //      idx, broadcasts winners via ibuf for P3 ----
  float* distf0 = (float*)accb;                  // 1024 f32
  int* candj0 = (int*)((char*)accb + 4096);      // 1024 i32
  float* distf1 = (float*)((char*)accb + 8192);  // 1024 f32
  int* candj1 = (int*)((char*)accb + 12288);     // 1024 i32
  int* ibuf = (int*)((char*)accb + 16384);       // 128 i32
  distf0[tid] = best0; candj0[tid] = bj0;
  distf1[tid] = best1; candj1[tid] = bj1;
  __syncthreads();

  if (tid < 64) {
    float bd0 = distf0[tl], bd1 = distf1[tl];
    int ci0 = candj0[tl], ci1 = candj1[tl];
#pragma unroll
    for (int qq = 1; qq < 16; ++qq) {
      float dd = distf0[qq * 64 + tl];
      int jj = candj0[qq * 64 + tl];
      if (dd < bd0) { bd0 = dd; ci0 = jj; }  // strict <: low slice wins
      dd = distf1[qq * 64 + tl];
      jj = candj1[qq * 64 + tl];
      if (dd < bd1) { bd1 = dd; ci1 = jj; }
    }
    ibuf[tl] = ci0; ibuf[64 + tl] = ci1;
    float2 iv; iv.x = (float)ci0; iv.y = (float)ci1;
    *(float2*)(oidx + (size_t)b * T_ + t0) = iv;
  }
  __syncthreads();
  const int bi0 = ibuf[tl];
  const int bi1 = ibuf[64 + tl];

  // raw codebook rows for loss + back-projection (divergent 32B gathers)
  float cq0[8], cq1[8];
  {
    const float* cp0 = cbraw + (size_t)bi0 * 8;
    const float* cp1 = cbraw + (size_t)bi1 * 8;
#pragma unroll
    for (int c = 0; c < 8; ++c) { cq0[c] = cp0[c]; cq1[c] = cp1[c]; }
  }

  // ---- loss partial (wave 0 only; all waves hold identical e, cq) ----
  if (tid < 64) {
    float lsum = 0.f;
#pragma unroll
    for (int c = 0; c < 8; ++c) {
      const float df0 = __fsub_rn(e0[c], cq0[c]);
      lsum = fmaf(df0, df0, lsum);
    }
#pragma unroll
    for (int c = 0; c < 8; ++c) {
      const float df1 = __fsub_rn(e1[c], cq1[c]);
      lsum = fmaf(df1, df1, lsum);
    }
#pragma unroll
    for (int off = 32; off > 0; off >>= 1)
      lsum += __shfl_down(lsum, off, 64);
    if (tl == 0) lossp[blk] = lsum;
  }

  // ---- phase 3: out[b,d,{t0,t0+1}] over this wave's 64-d slice ----
  float2* op2 =
      (float2*)(out + ((size_t)b * D_ + (size_t)q0 * 64) * T_ + t0);
  const float* woq = wo16 + (size_t)q0 * 1024;  // uniform -> s_load
#pragma unroll 4
  for (int d = 0; d < 64; ++d) {
    const float* row = woq + d * 16;
    const float4 lo = *(const float4*)(row);
    const float4 hi = *(const float4*)(row + 4);
    const float bo = row[8];
    float d0 = 0.f, d1 = 0.f;
    d0 = fmaf(cq0[0], lo.x, d0); d1 = fmaf(cq1[0], lo.x, d1);
    d0 = fmaf(cq0[1], lo.y, d0); d1 = fmaf(cq1[1], lo.y, d1);
    d0 = fmaf(cq0[2], lo.z, d0); d1 = fmaf(cq1[2], lo.z, d1);
    d0 = fmaf(cq0[3], lo.w, d0); d1 = fmaf(cq1[3], lo.w, d1);
    d0 = fmaf(cq0[4], hi.x, d0); d1 = fmaf(cq1[4], hi.x, d1);
    d0 = fmaf(cq0[5], hi.y, d0); d1 = fmaf(cq1[5], hi.y, d1);
    d0 = fmaf(cq0[6], hi.z, d0); d1 = fmaf(cq1[6], hi.z, d1);
    d0 = fmaf(cq0[7], hi.w, d0); d1 = fmaf(cq1[7], hi.w, d1);
    float2 ov; ov.x = __fadd_rn(d0, bo); ov.y = __fadd_rn(d1, bo);
    op2[(size_t)d * (T_ / 2)] = ov;
  }
}

// ---------- finalize loss ----------
__global__ __launch_bounds__(64) void vq_fin(const float* __restrict__ lossp,
                                             float* __restrict__ oloss) {
  const int tid = threadIdx.x;
  if (tid < B_) {
    float s = 0.f;
    for (int i = 0; i < 32; ++i) s += lossp[tid * 32 + i];
    oloss[tid] = s * (1.25f / 32768.0f);
  }
}

extern "C" void kernel_launch(void* const* d_in, const int* in_sizes, int n_in,
                              void* d_out, int out_size, void* d_ws,
                              size_t ws_size, hipStream_t stream) {
  (void)in_sizes; (void)n_in; (void)out_size; (void)ws_size;
  const float* z = (const float*)d_in[0];
  const float* cb = (const float*)d_in[1];
  const float* g_in = (const float*)d_in[2];
  const float* v_in = (const float*)d_in[3];
  const float* b_in = (const float*)d_in[4];
  const float* g_out = (const float*)d_in[5];
  const float* v_out = (const float*)d_in[6];
  const float* b_out = (const float*)d_in[7];
  float* out = (float*)d_out;

  char* ws = (char*)d_ws;
  double* WTd = (double*)ws;              // 65536 B
  float* cb16 = (float*)(ws + 65536);     // 65536 B
  float* wo16 = (float*)(ws + 131072);    // 65536 B
  float* lossp = (float*)(ws + 196608);   // 2048 B

  float* oidx = out + (size_t)B_ * D_ * T_;
  float* oloss = oidx + (size_t)B_ * T_;

  vq_setup<<<1, 1024, 0, stream>>>(cb, g_in, v_in, g_out, v_out, b_out, WTd,
                                   cb16, wo16);
  vq_main<<<512, 1024, 0, stream>>>(z, cb, b_in, WTd, cb16, wo16, out, oidx,
                                    lossp);
  vq_fin<<<1, 64, 0, stream>>>(lossp, oloss);
}